// Round 1
// baseline (83.301 us; speedup 1.0000x reference)
//
#include <hip/hip_runtime.h>

// ParallelLinear: out[b,t,o] = sum_i x[b,t,i] * W[t,o,i] + bias[t,o]
// B=512, T=1024, ISIZE=OSIZE=64, fp32.
//
// Block = 256 threads, one t, 256 rows of B. Thread computes an 8x8 tile
// -> LDS delivery halves to 1 B/FMA, all LDS ops are b128.
// Xs transposed [i][r] with XOR-swizzled 16B granules; Wt transposed [i][o].
// LDS = 80 KB -> 2 blocks/CU.

#define T_DIM 1024
#define B_DIM 512
#define KSZ 64
#define OSZ 64
#define ROWS 256

__global__ __launch_bounds__(256, 2) void pl_kernel(
    const float* __restrict__ x,
    const float* __restrict__ W,
    const float* __restrict__ bias,
    float* __restrict__ out)
{
    __shared__ float Xs[KSZ * ROWS];   // Xs[i*ROWS + swz(r)]  (64 x 256)
    __shared__ float Wt[KSZ * OSZ];    // Wt[i*OSZ + o]        (64 x 64)

    const int t     = blockIdx.x >> 1;
    const int chunk = blockIdx.x & 1;
    const int row0  = chunk * ROWS;
    const int tid   = threadIdx.x;

    // ---- stage W[t] transposed: thread o = tid&63 reads W[t][o][ib..ib+15] ----
    {
        const int o  = tid & 63;
        const int ib = (tid >> 6) << 4;      // 0,16,32,48 (wave-uniform)
        const float* wg = W + (size_t)t * (OSZ * KSZ) + (size_t)o * KSZ + ib;
        #pragma unroll
        for (int c = 0; c < 4; ++c) {
            float4 wv = *(const float4*)(wg + 4 * c);
            // lanes write consecutive o at fixed i -> conflict-free
            Wt[(ib + 4 * c + 0) * OSZ + o] = wv.x;
            Wt[(ib + 4 * c + 1) * OSZ + o] = wv.y;
            Wt[(ib + 4 * c + 2) * OSZ + o] = wv.z;
            Wt[(ib + 4 * c + 3) * OSZ + o] = wv.w;
        }
    }

    // ---- stage X tile transposed via 4x4 register transpose ----
    // thread (g=tid>>4, q=tid&15): rows 64*it+4g..+3, cols 4q..4q+3
    {
        const int g = tid >> 4;
        const int q = tid & 15;
        #pragma unroll
        for (int it = 0; it < 4; ++it) {
            const int r0 = 64 * it + 4 * g;
            const float* xg = x + ((size_t)(row0 + r0) * T_DIM + t) * KSZ + 4 * q;
            float4 a0 = *(const float4*)(xg);
            float4 a1 = *(const float4*)(xg + (size_t)T_DIM * KSZ);
            float4 a2 = *(const float4*)(xg + 2 * (size_t)T_DIM * KSZ);
            float4 a3 = *(const float4*)(xg + 3 * (size_t)T_DIM * KSZ);
            // transpose 4x4: v[cc] = column cc = rows r0..r0+3 at i=4q+cc
            float4 v0 = make_float4(a0.x, a1.x, a2.x, a3.x);
            float4 v1 = make_float4(a0.y, a1.y, a2.y, a3.y);
            float4 v2 = make_float4(a0.z, a1.z, a2.z, a3.z);
            float4 v3 = make_float4(a0.w, a1.w, a2.w, a3.w);
            // granule swizzle: g' = (r>>2) ^ ((i>>2)&7); here i>>2 == q for cc=0..3
            const int gsw = (((16 * it + g) ^ (q & 7)) << 2);
            *(float4*)&Xs[(4 * q + 0) * ROWS + gsw] = v0;
            *(float4*)&Xs[(4 * q + 1) * ROWS + gsw] = v1;
            *(float4*)&Xs[(4 * q + 2) * ROWS + gsw] = v2;
            *(float4*)&Xs[(4 * q + 3) * ROWS + gsw] = v3;
        }
    }

    __syncthreads();

    // ---- compute: thread (tr,tc) does rows 8tr..8tr+7, cols 8tc..8tc+7 ----
    const int tr = tid >> 3;             // 0..31
    const int tc = tid & 7;              // 0..7

    float acc[8][8] = {};

    #pragma unroll 4
    for (int i = 0; i < KSZ; ++i) {
        const int f = (i >> 2) & 7;      // constant within each unroll-of-4 group
        float4 xa = *(const float4*)&Xs[i * ROWS + (((2 * tr)     ^ f) << 2)];
        float4 xb = *(const float4*)&Xs[i * ROWS + (((2 * tr + 1) ^ f) << 2)];
        float4 wa = *(const float4*)&Wt[i * OSZ + 8 * tc];
        float4 wb = *(const float4*)&Wt[i * OSZ + 8 * tc + 4];
        float xs[8] = {xa.x, xa.y, xa.z, xa.w, xb.x, xb.y, xb.z, xb.w};
        float ws[8] = {wa.x, wa.y, wa.z, wa.w, wb.x, wb.y, wb.z, wb.w};
        #pragma unroll
        for (int r = 0; r < 8; ++r)
            #pragma unroll
            for (int c = 0; c < 8; ++c)
                acc[r][c] += xs[r] * ws[c];   // contracts to v_fmac like baseline
    }

    // ---- epilogue: bias + 2 float4 stores per row ----
    float4 bv0 = *(const float4*)(bias + (size_t)t * OSZ + 8 * tc);
    float4 bv1 = *(const float4*)(bias + (size_t)t * OSZ + 8 * tc + 4);
    #pragma unroll
    for (int r = 0; r < 8; ++r) {
        const size_t b = (size_t)row0 + 8 * tr + r;
        float* op = out + (b * T_DIM + t) * OSZ + 8 * tc;
        float4 o0, o1;
        o0.x = acc[r][0] + bv0.x; o0.y = acc[r][1] + bv0.y;
        o0.z = acc[r][2] + bv0.z; o0.w = acc[r][3] + bv0.w;
        o1.x = acc[r][4] + bv1.x; o1.y = acc[r][5] + bv1.y;
        o1.z = acc[r][6] + bv1.z; o1.w = acc[r][7] + bv1.w;
        *(float4*)(op)     = o0;
        *(float4*)(op + 4) = o1;
    }
}

extern "C" void kernel_launch(void* const* d_in, const int* in_sizes, int n_in,
                              void* d_out, int out_size, void* d_ws, size_t ws_size,
                              hipStream_t stream) {
    const float* x    = (const float*)d_in[0];
    const float* W    = (const float*)d_in[1];
    const float* bias = (const float*)d_in[2];
    float* out        = (float*)d_out;

    dim3 grid(T_DIM * (B_DIM / ROWS));   // 1024 * 2 = 2048 blocks
    dim3 block(256);
    pl_kernel<<<grid, block, 0, stream>>>(x, W, bias, out);
}

// Round 2
// 78.766 us; speedup vs baseline: 1.0576x; 1.0576x over previous
//
#include <hip/hip_runtime.h>

// ParallelLinear: out[b,t,o] = sum_i x[b,t,i] * W[t,o,i] + bias[t,o]
// B=512, T=1024, ISIZE=OSIZE=64, fp32.
//
// Latency-bound regime (all pipes <40%) -> maximize waves/CU.
// Block = 256 threads, one t, 64 rows of B, 4x4 thread tile (round-0 geometry).
// LDS = 16KB Wt + 16KB Xs = exactly 32KB -> 5 blocks/CU = 20 waves/CU.
// Inner loop: 2 x ds_read_b128 (X transposed+swizzled, W transposed) + 16 FMA.

#define T_DIM 1024
#define B_DIM 512
#define KSZ 64
#define OSZ 64
#define ROWS 64

__global__ __launch_bounds__(256, 5) void pl_kernel(
    const float* __restrict__ x,
    const float* __restrict__ W,
    const float* __restrict__ bias,
    float* __restrict__ out)
{
    __shared__ float Wt[KSZ * OSZ];    // Wt[i*64 + o] = W[t][o][i]
    __shared__ float Xs[KSZ * ROWS];   // Xs[i*64 + ((g^(i>>2))<<2) + k] = x[row0+4g+k][t][i]

    const int t     = blockIdx.x >> 3;   // 0..1023
    const int chunk = blockIdx.x & 7;    // 0..7
    const int row0  = chunk * ROWS;
    const int tid   = threadIdx.x;

    // ---- stage W[t] transposed: thread o = tid&63 reads W[t][o][ib..ib+15] ----
    // LDS writes: lanes write consecutive o at fixed i -> 2-way (free).
    {
        const int o  = tid & 63;
        const int ib = (tid >> 6) << 4;      // 0,16,32,48 (wave-uniform)
        const float* wg = W + (size_t)t * (OSZ * KSZ) + (size_t)o * KSZ + ib;
        #pragma unroll
        for (int c = 0; c < 4; ++c) {
            float4 wv = *(const float4*)(wg + 4 * c);
            Wt[(ib + 4 * c + 0) * OSZ + o] = wv.x;
            Wt[(ib + 4 * c + 1) * OSZ + o] = wv.y;
            Wt[(ib + 4 * c + 2) * OSZ + o] = wv.z;
            Wt[(ib + 4 * c + 3) * OSZ + o] = wv.w;
        }
    }

    // ---- stage X tile transposed via 4x4 register transpose ----
    // thread (g=tid>>4, q=tid&15): rows 4g..4g+3, cols 4q..4q+3.
    // Granule swizzle: data granule g of row i lives at position g ^ (i>>2).
    {
        const int g = tid >> 4;
        const int q = tid & 15;
        const float* xg = x + ((size_t)(row0 + 4 * g) * T_DIM + t) * KSZ + 4 * q;
        float4 a0 = *(const float4*)(xg);
        float4 a1 = *(const float4*)(xg + (size_t)T_DIM * KSZ);
        float4 a2 = *(const float4*)(xg + 2 * (size_t)T_DIM * KSZ);
        float4 a3 = *(const float4*)(xg + 3 * (size_t)T_DIM * KSZ);
        float4 v0 = make_float4(a0.x, a1.x, a2.x, a3.x);   // col 4q+0, rows 4g..4g+3
        float4 v1 = make_float4(a0.y, a1.y, a2.y, a3.y);
        float4 v2 = make_float4(a0.z, a1.z, a2.z, a3.z);
        float4 v3 = make_float4(a0.w, a1.w, a2.w, a3.w);
        const int p = (g ^ q) << 2;                        // i>>2 == q for these 4 cols
        *(float4*)&Xs[(4 * q + 0) * ROWS + p] = v0;
        *(float4*)&Xs[(4 * q + 1) * ROWS + p] = v1;
        *(float4*)&Xs[(4 * q + 2) * ROWS + p] = v2;
        *(float4*)&Xs[(4 * q + 3) * ROWS + p] = v3;
    }

    __syncthreads();

    // ---- compute: thread (tr,tc) does rows 4tr..4tr+3, cols 4tc..4tc+3 ----
    const int tr = tid >> 4;             // 0..15
    const int tc = tid & 15;             // 0..15

    float acc[4][4] = {};

    #pragma unroll 8
    for (int i = 0; i < KSZ; ++i) {
        const int f = i >> 2;
        float4 xv = *(const float4*)&Xs[i * ROWS + ((tr ^ f) << 2)];  // rows 4tr..4tr+3 at col i
        float4 wv = *(const float4*)&Wt[i * OSZ + (tc << 2)];         // cols 4tc..4tc+3 at i
        acc[0][0] += xv.x * wv.x; acc[0][1] += xv.x * wv.y; acc[0][2] += xv.x * wv.z; acc[0][3] += xv.x * wv.w;
        acc[1][0] += xv.y * wv.x; acc[1][1] += xv.y * wv.y; acc[1][2] += xv.y * wv.z; acc[1][3] += xv.y * wv.w;
        acc[2][0] += xv.z * wv.x; acc[2][1] += xv.z * wv.y; acc[2][2] += xv.z * wv.z; acc[2][3] += xv.z * wv.w;
        acc[3][0] += xv.w * wv.x; acc[3][1] += xv.w * wv.y; acc[3][2] += xv.w * wv.z; acc[3][3] += xv.w * wv.w;
    }

    // ---- epilogue: add bias, store float4 per row ----
    float4 bv = *(const float4*)(bias + (size_t)t * OSZ + (tc << 2));
    #pragma unroll
    for (int k = 0; k < 4; ++k) {
        int b = row0 + tr * 4 + k;
        float4 res;
        res.x = acc[k][0] + bv.x;
        res.y = acc[k][1] + bv.y;
        res.z = acc[k][2] + bv.z;
        res.w = acc[k][3] + bv.w;
        *(float4*)(out + ((size_t)b * T_DIM + t) * OSZ + (tc << 2)) = res;
    }
}

extern "C" void kernel_launch(void* const* d_in, const int* in_sizes, int n_in,
                              void* d_out, int out_size, void* d_ws, size_t ws_size,
                              hipStream_t stream) {
    const float* x    = (const float*)d_in[0];
    const float* W    = (const float*)d_in[1];
    const float* bias = (const float*)d_in[2];
    float* out        = (float*)d_out;

    dim3 grid(T_DIM * (B_DIM / ROWS));   // 8192 blocks
    dim3 block(256);
    pl_kernel<<<grid, block, 0, stream>>>(x, W, bias, out);
}

// Round 3
// 75.924 us; speedup vs baseline: 1.0972x; 1.0374x over previous
//
#include <hip/hip_runtime.h>

// ParallelLinear: out[b,t,o] = sum_i x[b,t,i] * W[t,o,i] + bias[t,o]
// B=512, T=1024, ISIZE=OSIZE=64, fp32.
//
// Persistent-per-t pipeline: grid = 1024 blocks (one per t), each runs all 8
// chunks of 64 rows. W[t] staged to LDS once. X chunk c+1 is prefetched into
// registers while chunk c computes (T14 issue-early/write-late), so global
// latency hides under the FMA phase. LDS = 16KB Wt + 16KB Xs = 32KB ->
// all 1024 blocks co-resident (4/CU), zero churn.

#define T_DIM 1024
#define B_DIM 512
#define KSZ 64
#define OSZ 64
#define ROWS 64
#define NCHUNK (B_DIM / ROWS)   // 8

__global__ __launch_bounds__(256, 4) void pl_kernel(
    const float* __restrict__ x,
    const float* __restrict__ W,
    const float* __restrict__ bias,
    float* __restrict__ out)
{
    __shared__ float Wt[KSZ * OSZ];    // Wt[i*64 + o] = W[t][o][i]
    __shared__ float Xs[KSZ * ROWS];   // Xs[i*64 + ((g^(i>>2))<<2) + k], transposed+swizzled

    const int t   = blockIdx.x;        // 0..1023
    const int tid = threadIdx.x;

    // ---- stage W[t] transposed, once per block ----
    {
        const int o  = tid & 63;
        const int ib = (tid >> 6) << 4;      // 0,16,32,48 (wave-uniform)
        const float* wg = W + (size_t)t * (OSZ * KSZ) + (size_t)o * KSZ + ib;
        #pragma unroll
        for (int cc = 0; cc < 4; ++cc) {
            float4 wv = *(const float4*)(wg + 4 * cc);
            // lanes write consecutive o at fixed i -> conflict-free
            Wt[(ib + 4 * cc + 0) * OSZ + o] = wv.x;
            Wt[(ib + 4 * cc + 1) * OSZ + o] = wv.y;
            Wt[(ib + 4 * cc + 2) * OSZ + o] = wv.z;
            Wt[(ib + 4 * cc + 3) * OSZ + o] = wv.w;
        }
    }

    const int g = tid >> 4;              // 0..15  (stage row-group == compute tr)
    const int q = tid & 15;              // 0..15  (stage col-group == compute tc)

    const size_t rstride = (size_t)T_DIM * KSZ;     // floats per b-row
    const size_t cstride = (size_t)ROWS * rstride;  // floats per 64-row chunk
    const float* xg0 = x + ((size_t)(4 * g) * T_DIM + t) * KSZ + 4 * q;

    // ---- prefetch chunk 0 into registers ----
    float4 a0, a1, a2, a3;
    {
        const float* p = xg0;
        a0 = *(const float4*)(p);
        a1 = *(const float4*)(p + rstride);
        a2 = *(const float4*)(p + 2 * rstride);
        a3 = *(const float4*)(p + 3 * rstride);
    }

    const float4 bv = *(const float4*)(bias + (size_t)t * OSZ + (q << 2));

    for (int c = 0; c < NCHUNK; ++c) {
        // 4x4 register transpose of chunk c (implicit vmcnt wait on its loads,
        // overlapped with other waves still computing chunk c-1)
        float4 v0 = make_float4(a0.x, a1.x, a2.x, a3.x);
        float4 v1 = make_float4(a0.y, a1.y, a2.y, a3.y);
        float4 v2 = make_float4(a0.z, a1.z, a2.z, a3.z);
        float4 v3 = make_float4(a0.w, a1.w, a2.w, a3.w);

        if (c > 0) __syncthreads();      // all waves done reading Xs for c-1

        const int p = (g ^ q) << 2;      // granule swizzle: pos = g ^ (i>>2), i>>2==q here
        *(float4*)&Xs[(4 * q + 0) * ROWS + p] = v0;
        *(float4*)&Xs[(4 * q + 1) * ROWS + p] = v1;
        *(float4*)&Xs[(4 * q + 2) * ROWS + p] = v2;
        *(float4*)&Xs[(4 * q + 3) * ROWS + p] = v3;

        // issue chunk c+1 loads now; they complete under the compute below
        if (c + 1 < NCHUNK) {
            const float* pn = xg0 + (size_t)(c + 1) * cstride;
            a0 = *(const float4*)(pn);
            a1 = *(const float4*)(pn + rstride);
            a2 = *(const float4*)(pn + 2 * rstride);
            a3 = *(const float4*)(pn + 3 * rstride);
        }

        __syncthreads();                 // Xs(c) visible to all waves

        // ---- compute: thread (g,q) does rows 4g..4g+3, cols 4q..4q+3 ----
        float acc[4][4] = {};
        #pragma unroll 8
        for (int i = 0; i < KSZ; ++i) {
            const int f = i >> 2;
            float4 xv = *(const float4*)&Xs[i * ROWS + ((g ^ f) << 2)];
            float4 wv = *(const float4*)&Wt[i * OSZ + (q << 2)];
            acc[0][0] += xv.x * wv.x; acc[0][1] += xv.x * wv.y; acc[0][2] += xv.x * wv.z; acc[0][3] += xv.x * wv.w;
            acc[1][0] += xv.y * wv.x; acc[1][1] += xv.y * wv.y; acc[1][2] += xv.y * wv.z; acc[1][3] += xv.y * wv.w;
            acc[2][0] += xv.z * wv.x; acc[2][1] += xv.z * wv.y; acc[2][2] += xv.z * wv.z; acc[2][3] += xv.z * wv.w;
            acc[3][0] += xv.w * wv.x; acc[3][1] += xv.w * wv.y; acc[3][2] += xv.w * wv.z; acc[3][3] += xv.w * wv.w;
        }

        // ---- epilogue: bias + float4 store per row ----
        const int row0 = c * ROWS;
        #pragma unroll
        for (int k = 0; k < 4; ++k) {
            const int b = row0 + g * 4 + k;
            float4 res;
            res.x = acc[k][0] + bv.x;
            res.y = acc[k][1] + bv.y;
            res.z = acc[k][2] + bv.z;
            res.w = acc[k][3] + bv.w;
            *(float4*)(out + ((size_t)b * T_DIM + t) * OSZ + (q << 2)) = res;
        }
    }
}

extern "C" void kernel_launch(void* const* d_in, const int* in_sizes, int n_in,
                              void* d_out, int out_size, void* d_ws, size_t ws_size,
                              hipStream_t stream) {
    const float* x    = (const float*)d_in[0];
    const float* W    = (const float*)d_in[1];
    const float* bias = (const float*)d_in[2];
    float* out        = (float*)d_out;

    dim3 grid(T_DIM);                    // 1024 persistent blocks, one per t
    dim3 block(256);
    pl_kernel<<<grid, block, 0, stream>>>(x, W, bias, out);
}